// Round 20
// baseline (116.985 us; speedup 1.0000x reference)
//
#include <hip/hip_runtime.h>
#include <hip/hip_bf16.h>

// ---------------- types ----------------
typedef float f32x4 __attribute__((ext_vector_type(4)));
typedef float f32x16 __attribute__((ext_vector_type(16)));
typedef __bf16 v8bf __attribute__((ext_vector_type(8)));
typedef unsigned short ushortx4 __attribute__((ext_vector_type(4)));
typedef unsigned short ushortx8 __attribute__((ext_vector_type(8)));
typedef unsigned int uint4v __attribute__((ext_vector_type(4)));

#define NIMG 16
#define CCH  256
#define HWP  1600

// q pre-scale: (1/sqrt(256)) * log2(e)  -> softmax runs in log2 domain (v_exp_f32 = 2^x)
#define QSCALE 0.09016844f
#define DEFER_THR 11.541560f   // 8.0 * log2(e)  (T13 defer-rescale, HK threshold)

__device__ __forceinline__ unsigned short f2bf(float f) {
  unsigned int u = __builtin_bit_cast(unsigned int, f);
  u = (u + 0x7FFFu + ((u >> 16) & 1u)) >> 16;
  return (unsigned short)u;
}
__device__ __forceinline__ float bf2f(unsigned short u) {
  return __builtin_bit_cast(float, (unsigned int)u << 16);
}

__device__ __forceinline__ f32x4 mfma16(v8bf a, v8bf b, f32x4 c) {
  return __builtin_amdgcn_mfma_f32_16x16x32_bf16(a, b, c, 0, 0, 0);
}
__device__ __forceinline__ f32x16 mfma32(v8bf a, v8bf b, f32x16 c) {
  return __builtin_amdgcn_mfma_f32_32x32x16_bf16(a, b, c, 0, 0, 0);
}

__device__ __forceinline__ unsigned cvtpk(float a, float b) {
  unsigned r;
  asm("v_cvt_pk_bf16_f32 %0, %1, %2" : "=v"(r) : "v"(a), "v"(b));
  return r;
}
__device__ __forceinline__ float exp2v(float x) {
  float r;
  asm("v_exp_f32 %0, %1" : "=v"(r) : "v"(x));
  return r;
}
__device__ __forceinline__ float sin2pi(float rev) {   // sin(2*pi*rev), rev >= 0
  float r;
  asm("v_fract_f32 %0, %1\n\tv_sin_f32 %0, %0" : "=v"(r) : "v"(rev));
  return r;
}
#define PSWAP(a, b) asm("v_permlane32_swap_b32 %0, %1" : "+v"(a), "+v"(b))

// ---------------- kernel A: weight->bf16 frag repack + PE table (bf16, native trig) --------
__global__ void prep_kernel(const float* __restrict__ qkv_w,
                            unsigned short* __restrict__ pe16,
                            unsigned short* __restrict__ w_frag) {
  int tid = blockIdx.x * blockDim.x + threadIdx.x;
  int nthr = gridDim.x * blockDim.x;
  for (int i = tid; i < 768 * 256; i += nthr) {
    int o = i >> 8, c = i & 255;
    int tile = o >> 4, lr = o & 15;
    int ks = c >> 5, lg = (c >> 3) & 3, e = c & 7;
    w_frag[(((size_t)tile * 8 + ks) * 64 + lg * 16 + lr) * 8 + e] = f2bf(qkv_w[i]);
  }
  const float oc = 0.20762051f;        // log2(10000)/64
  const float inv2pi = 0.15915494f;    // 1/(2*pi)
  for (int i = tid; i < HWP * 256; i += nthr) {
    int p = i >> 8, c = i & 255;
    int j = p % 40, ii = p / 40;             // x = j (col), y = ii (row)
    int tt = c & 63;
    float omega = exp2v(-(float)tt * oc) * inv2pi;
    float coord = (c < 128) ? (float)j : (float)ii;
    float rev = coord * omega;               // angle in revolutions
    if (c & 64) rev += 0.25f;                // cos(x) = sin(x + pi/2)
    pe16[i] = f2bf(sin2pi(rev));
  }
}

// ---------------- kernel B: LN + QKV GEMM + PE, direct frag-layout stores ----------------
// x read ONCE (kept in xv[32] registers across the LN stats phase; dead before GEMM).
// PE table is bf16 and loaded ONCE per (pix,c) -> shared by the q and k epilogues.
__global__ __launch_bounds__(512, 4) void ln_qkv_kernel(
    const float* __restrict__ x, const float* __restrict__ ln_w, const float* __restrict__ ln_b,
    const unsigned short* __restrict__ w_frag, const float* __restrict__ qkv_b,
    const unsigned short* __restrict__ pe16,
    unsigned short* __restrict__ q_arr, unsigned short* __restrict__ k_arr,
    unsigned short* __restrict__ v_arr) {
  __shared__ unsigned short bufraw[18432];     // 36,864 B
  __shared__ float red_s[8][64], red_q[8][64];
  __shared__ float mu_s[64], rs_s[64];

  int t = threadIdx.x;
  int n = blockIdx.x / 25, pt = blockIdx.x % 25;
  int pix0 = pt * 64;
  int p = t & 63, g = t >> 6;
  const float* xb = x + (size_t)n * CCH * HWP + pix0;

  // pass 1: LN stats; x kept in registers (single HBM read)
  float xv[32];
  {
    float sum = 0.f, sq = 0.f;
#pragma unroll
    for (int i = 0; i < 32; ++i) {
      float v = xb[(size_t)(g * 32 + i) * HWP + p];
      xv[i] = v; sum += v; sq += v * v;
    }
    red_s[g][p] = sum; red_q[g][p] = sq;
  }
  __syncthreads();
  if (t < 64) {
    float s = 0.f, q2 = 0.f;
#pragma unroll
    for (int gg = 0; gg < 8; ++gg) { s += red_s[gg][t]; q2 += red_q[gg][t]; }
    float mu = s * (1.f / 256.f);
    float var = q2 * (1.f / 256.f) - mu * mu;
    mu_s[t] = mu;
    rs_s[t] = rsqrtf(var + 1e-5f);
  }
  __syncthreads();
  {
    float mu = mu_s[p], rs = rs_s[p];
    int p7 = p & 7;
#pragma unroll
    for (int i4 = 0; i4 < 8; ++i4) {
      int c0 = g * 32 + i4 * 4;
      f32x4 lw = *(const f32x4*)&ln_w[c0];
      f32x4 lb = *(const f32x4*)&ln_b[c0];
      ushortx4 pk;
#pragma unroll
      for (int r = 0; r < 4; ++r)
        pk[r] = f2bf((xv[i4 * 4 + r] - mu) * rs * lw[r] + lb[r]);
      int unit = (c0 >> 3) ^ p7;             // swizzled 16B unit
      *(ushortx4*)&bufraw[p * 256 + unit * 8 + (i4 & 1) * 4] = pk;
    }
  }
  __syncthreads();

  // GEMM: A = weights (frag-arranged global), B = x-tile (LDS, swizzled reads)
  int w = t >> 6, l = t & 63, lr = l & 15, lg = l >> 4;
  int lr7 = lr & 7;
  f32x4 acc[6][4];
#pragma unroll
  for (int nf = 0; nf < 6; ++nf)
#pragma unroll
    for (int mi = 0; mi < 4; ++mi) acc[nf][mi] = (f32x4){0.f, 0.f, 0.f, 0.f};

#pragma unroll
  for (int ks = 0; ks < 8; ++ks) {
    v8bf bF[4];
#pragma unroll
    for (int mi = 0; mi < 4; ++mi)
      bF[mi] = *(const v8bf*)&bufraw[(mi * 16 + lr) * 256 + (((ks * 4 + lg) ^ lr7) * 8)];
#pragma unroll
    for (int nf = 0; nf < 6; ++nf) {
      int tile = w + nf * 8;
      v8bf wf = *(const v8bf*)&w_frag[(((size_t)tile * 8 + ks) * 64 + l) * 8];
#pragma unroll
      for (int mi = 0; mi < 4; ++mi) acc[nf][mi] = mfma16(wf, bF[mi], acc[nf][mi]);
    }
  }
  __syncthreads();   // A-tile dead chip-wide; bufraw reused as V stage

  // epilogue: acc[nf][mi][r] -> channel o = tile*16+lg*4+r, pixel pix0+mi*16+lr
  int lgh = lg >> 1, lgl = lg & 1;

  // ---- v (tiles 32..47): +bias -> wave-private LDS transpose stage ----
#pragma unroll
  for (int nf = 4; nf < 6; ++nf) {
    int tile = w + nf * 8;
    f32x4 bi = *(const f32x4*)&qkv_b[tile * 16 + lg * 4];
    int chb = (nf - 4) * 16 + lg * 4;
#pragma unroll
    for (int mi = 0; mi < 4; ++mi) {
      int pixl = mi * 16 + lr;
      f32x4 vv = acc[nf][mi] + bi;
#pragma unroll
      for (int r = 0; r < 4; ++r)
        bufraw[(w * 32 + chb + r) * 72 + pixl] = f2bf(vv[r]);
    }
  }

  // ---- q (tiles 0..15) + k (tiles 16..31): shared PE load (identical values) ----
#pragma unroll
  for (int nf = 0; nf < 2; ++nf) {
    int tile = w + nf * 8;          // q tile; k tile = tile+16, same pe slice
    int c4 = tile * 16 + lg * 4;
    f32x4 biq = *(const f32x4*)&qkv_b[c4];
    f32x4 bik = *(const f32x4*)&qkv_b[256 + c4];
#pragma unroll
    for (int mi = 0; mi < 4; ++mi) {
      int pix = pix0 + mi * 16 + lr;
      ushortx4 pu = *(const ushortx4*)&pe16[(size_t)pix * 256 + c4];
      f32x4 pev = {bf2f(pu[0]), bf2f(pu[1]), bf2f(pu[2]), bf2f(pu[3])};
      // q
      f32x4 vq = (acc[nf][mi] + biq + pev) * QSCALE;
      ushortx4 pkq = {f2bf(vq[0]), f2bf(vq[1]), f2bf(vq[2]), f2bf(vq[3])};
      int qt = pix >> 5, l31 = pix & 31;
      size_t adq = ((((size_t)n * 50 + qt) * 16 + tile) * 2 + lgh) * 256 + l31 * 8 + lgl * 4;
      *(ushortx4*)&q_arr[adq] = pkq;
      // k
      f32x4 vk = acc[nf + 2][mi] + bik + pev;
      ushortx4 pkk = {f2bf(vk[0]), f2bf(vk[1]), f2bf(vk[2]), f2bf(vk[3])};
      size_t adk = (((size_t)n * 16 + tile) * 1600 + pix) * 16 + lgh * 8 + lgl * 4;
      *(ushortx4*)&k_arr[adk] = pkk;
    }
  }

  // ---- v readback: 16B chunks from own wave's stage -> coalesced stores ----
#pragma unroll
  for (int c = 0; c < 4; ++c) {
    int ch = l & 31;                    // 0..31
    int pg = (l >> 5) + c * 2;          // 0..7
    ushortx8 vv = *(const ushortx8*)&bufraw[(w * 32 + ch) * 72 + pg * 8];
    int kvsl = pg >> 1, hi2 = pg & 1;
    int d = (ch & 15) + w * 16 + (ch >> 4) * 128;
    size_t di = (((size_t)n * 100 + pt * 4 + kvsl) * 2 + hi2) * 256 + d;
    *(ushortx8*)&v_arr[di * 8] = vv;
  }
}

// ---------------- kernel C: flash attention, 2 waves/block, D-split (r15 structure) --------
// KVBLK=64 per barrier; ONE lgkmcnt-only barrier per iteration. S partials written to
// LDS and read back by BOTH waves (fixed-order add -> bit-identical softmax, no final
// merge). QK(next) interleaved around the rescale branch; K single-buffered.
// r20 deltas: DEFER_THR = 8 ln-units (fewer acc rescales); V_B prefetch hoisted to
// right after the tile-A combine (load->use gap ~1400 cyc, zero register cost).
__global__ __launch_bounds__(128, 2) void attn_kernel(
    const unsigned short* __restrict__ q_arr, const unsigned short* __restrict__ k_arr,
    const unsigned short* __restrict__ v_arr, const float* __restrict__ x,
    const float* __restrict__ gamma, float* __restrict__ out) {
  __shared__ float sx[2][2][2][4][64][4];   // [slot][tileAB][wave][r4][lane][4] = 32 KB

  int t = threadIdx.x;
  int wv = t >> 6, l = t & 63;
  int l31 = l & 31, hi = l >> 5;
  int dto = wv * 8;      // 16-wide d-tile offset for q/k frags
  int dto32 = wv * 4;    // 32-wide d-tile offset for v/acc
  int slot = blockIdx.x & 7, j = blockIdx.x >> 3;   // j in 0..99
  int n = slot + 8 * (j / 50);
  int qt = j % 50;
  int q0 = qt * 32;

  v8bf qf[8];
  {
    const unsigned short* qp = q_arr + (((size_t)n * 50 + qt) * 32 + hi) * 256 + l31 * 8;
#pragma unroll
    for (int i = 0; i < 8; ++i)
      qf[i] = *(const v8bf*)(qp + (dto + i) * 512);
  }

  f32x16 acc[4];
#pragma unroll
  for (int dd = 0; dd < 4; ++dd)
#pragma unroll
    for (int r = 0; r < 16; ++r) acc[dd][r] = 0.f;

  float m_run = -1e30f, l_run = 0.f;

  const unsigned short* kbase = k_arr + (size_t)n * (16 * 1600 * 16) +
                                (size_t)dto * 25600 + hi * 8;
  const unsigned short* vbase = v_arr + (size_t)n * (100 * 2 * 256 * 8) +
                                hi * 2048 + l31 * 8 + dto32 * 256;

  v8bf kc[8];
  f32x16 s0, s1;

#define LOADK(TT)                                                              \
  {                                                                            \
    _Pragma("unroll")                                                          \
    for (int i = 0; i < 8; ++i)                                                \
      kc[i] = *(const v8bf*)(kbase + (size_t)i * 25600 + ((TT) * 32 + l31) * 16); \
  }
#define QKFULL()                                                               \
  {                                                                            \
    _Pragma("unroll")                                                          \
    for (int r = 0; r < 16; ++r) { s0[r] = 0.f; s1[r] = 0.f; }                 \
    _Pragma("unroll")                                                          \
    for (int i = 0; i < 8; i += 2) {                                           \
      s0 = mfma32(kc[i], qf[i], s0);                                           \
      s1 = mfma32(kc[i + 1], qf[i + 1], s1);                                   \
    }                                                                          \
  }
#define WRS(SL, TI)                                                            \
  {                                                                            \
    _Pragma("unroll")                                                          \
    for (int r4 = 0; r4 < 4; ++r4) {                                           \
      f32x4 vv = {s0[r4 * 4 + 0] + s1[r4 * 4 + 0], s0[r4 * 4 + 1] + s1[r4 * 4 + 1], \
                  s0[r4 * 4 + 2] + s1[r4 * 4 + 2], s0[r4 * 4 + 3] + s1[r4 * 4 + 3]}; \
      *(f32x4*)&sx[SL][TI][wv][r4][l][0] = vv;                                 \
    }                                                                          \
  }

  // ---- prologue: QK(0), QK(1) -> slot 0; kc <- K(2); vA <- V(0) ----
  LOADK(0); QKFULL(); WRS(0, 0);
  LOADK(1); QKFULL(); WRS(0, 1);
  LOADK(2);
  v8bf vA0[4], vA1[4], vB0[4], vB1[4];
#pragma unroll
  for (int i = 0; i < 4; ++i) vA0[i] = *(const v8bf*)(vbase + i * 256);
#pragma unroll
  for (int i = 0; i < 4; ++i) vA1[i] = *(const v8bf*)(vbase + 4096 + i * 256);

  for (int it = 0; it < 25; ++it) {
    int s = it & 1;
    bool more = (it < 24);
    asm volatile("s_waitcnt lgkmcnt(0)" ::: "memory");
    __builtin_amdgcn_s_barrier();

    // ================= tile A = 2*it =================
    float p[16];
#pragma unroll
    for (int r4 = 0; r4 < 4; ++r4) {
      f32x4 a = *(const f32x4*)&sx[s][0][0][r4][l][0];
      f32x4 b = *(const f32x4*)&sx[s][0][1][r4][l][0];
#pragma unroll
      for (int rr = 0; rr < 4; ++rr) p[r4 * 4 + rr] = a[rr] + b[rr];
    }
    // V_B <- V(2*it+1): hoisted here (consumed after softmax_B, ~1400 cyc slack)
    {
      const unsigned short* vp = vbase + (size_t)(2 * it + 1) * 8192;
#pragma unroll
      for (int i = 0; i < 4; ++i) vB0[i] = *(const v8bf*)(vp + i * 256);
#pragma unroll
      for (int i = 0; i < 4; ++i) vB1[i] = *(const v8bf*)(vp + 4096 + i * 256);
    }
    if (more) {   // QK(2*it+2) first half (MFMA pipe || VALU below)
#pragma unroll
      for (int r = 0; r < 16; ++r) { s0[r] = 0.f; s1[r] = 0.f; }
      s0 = mfma32(kc[0], qf[0], s0); s1 = mfma32(kc[1], qf[1], s1);
      s0 = mfma32(kc[2], qf[2], s0); s1 = mfma32(kc[3], qf[3], s1);
    }
    {
      float t0 = fmaxf(p[0], p[1]), t1 = fmaxf(p[2], p[3]);
      float t2 = fmaxf(p[4], p[5]), t3 = fmaxf(p[6], p[7]);
      float t4 = fmaxf(p[8], p[9]), t5 = fmaxf(p[10], p[11]);
      float t6 = fmaxf(p[12], p[13]), t7 = fmaxf(p[14], p[15]);
      float mx = fmaxf(fmaxf(fmaxf(t0, t1), fmaxf(t2, t3)),
                       fmaxf(fmaxf(t4, t5), fmaxf(t6, t7)));
      mx = fmaxf(mx, __shfl_xor(mx, 32));
      if (!__all(mx <= m_run + DEFER_THR)) {
        float mnew = fmaxf(m_run, mx);
        float alpha = exp2v(m_run - mnew);
        l_run *= alpha;
#pragma unroll
        for (int dd = 0; dd < 4; ++dd)
#pragma unroll
          for (int r = 0; r < 16; ++r) acc[dd][r] *= alpha;
        m_run = mnew;
      }
    }
    if (more) {   // QK(2*it+2) second half; write; prefetch K(2*it+3)
      s0 = mfma32(kc[4], qf[4], s0); s1 = mfma32(kc[5], qf[5], s1);
      s0 = mfma32(kc[6], qf[6], s0); s1 = mfma32(kc[7], qf[7], s1);
      WRS(s ^ 1, 0);
      LOADK(2 * it + 3);
    }
#pragma unroll
    for (int r = 0; r < 16; ++r) p[r] = exp2v(p[r] - m_run);
    {
      float sSum = ((p[0] + p[1]) + (p[2] + p[3])) + ((p[4] + p[5]) + (p[6] + p[7])) +
                   (((p[8] + p[9]) + (p[10] + p[11])) + ((p[12] + p[13]) + (p[14] + p[15])));
      sSum += __shfl_xor(sSum, 32);
      l_run += sSum;
    }
    {
      unsigned x0 = cvtpk(p[0], p[1]), x1 = cvtpk(p[2], p[3]);
      unsigned y0 = cvtpk(p[4], p[5]), y1 = cvtpk(p[6], p[7]);
      PSWAP(x0, y0); PSWAP(x1, y1);
      uint4v u0 = {x0, x1, y0, y1};
      v8bf pf0 = __builtin_bit_cast(v8bf, u0);
      unsigned z0 = cvtpk(p[8], p[9]), z1 = cvtpk(p[10], p[11]);
      unsigned w0 = cvtpk(p[12], p[13]), w1 = cvtpk(p[14], p[15]);
      PSWAP(z0, w0); PSWAP(z1, w1);
      uint4v u1 = {z0, z1, w0, w1};
      v8bf pf1 = __builtin_bit_cast(v8bf, u1);
      // PV_A
      acc[0] = mfma32(vA0[0], pf0, acc[0]); acc[1] = mfma32(vA0[1], pf0, acc[1]);
      acc[2] = mfma32(vA0[2], pf0, acc[2]); acc[3] = mfma32(vA0[3], pf0, acc[3]);
      acc[0] = mfma32(vA1[0], pf1, acc[0]); acc[1] = mfma32(vA1[1], pf1, acc[1]);
      acc[2] = mfma32(vA1[2], pf1, acc[2]); acc[3] = mfma32(vA1[3], pf1, acc[3]);
    }

    // ================= tile B = 2*it+1 =================
#pragma unroll
    for (int r4 = 0; r4 < 4; ++r4) {
      f32x4 a = *(const f32x4*)&sx[s][1][0][r4][l][0];
      f32x4 b = *(const f32x4*)&sx[s][1][1][r4][l][0];
#pragma unroll
      for (int rr = 0; rr < 4; ++rr) p[r4 * 4 + rr] = a[rr] + b[rr];
    }
    if (more) {   // V_A <- V(2*it+2): consumed next iter after softmax_A (~full-iter slack)
      const unsigned short* vp = vbase + (size_t)(2 * it + 2) * 8192;
#pragma unroll
      for (int i = 0; i < 4; ++i) vA0[i] = *(const v8bf*)(vp + i * 256);
#pragma unroll
      for (int i = 0; i < 4; ++i) vA1[i] = *(const v8bf*)(vp + 4096 + i * 256);
    }
    if (more) {   // QK(2*it+3) first half
#pragma unroll
      for (int r = 0; r < 16; ++r) { s0[r] = 0.f; s1[r] = 0.f; }
      s0 = mfma32(kc[0], qf[0], s0); s1 = mfma32(kc[1], qf[1], s1);
      s0 = mfma32(kc[2], qf[2], s0); s1 = mfma32(kc[3], qf[3], s1);
    }
    {
      float t0 = fmaxf(p[0], p[1]), t1 = fmaxf(p[2], p[3]);
      float t2 = fmaxf(p[4], p[5]), t3 = fmaxf(p[6], p[7]);
      float t4 = fmaxf(p[8], p[9]), t5 = fmaxf(p[10], p[11]);
      float t6 = fmaxf(p[12], p[13]), t7 = fmaxf(p[14], p[15]);
      float mx = fmaxf(fmaxf(fmaxf(t0, t1), fmaxf(t2, t3)),
                       fmaxf(fmaxf(t4, t5), fmaxf(t6, t7)));
      mx = fmaxf(mx, __shfl_xor(mx, 32));
      if (!__all(mx <= m_run + DEFER_THR)) {
        float mnew = fmaxf(m_run, mx);
        float alpha = exp2v(m_run - mnew);
        l_run *= alpha;
#pragma unroll
        for (int dd = 0; dd < 4; ++dd)
#pragma unroll
          for (int r = 0; r < 16; ++r) acc[dd][r] *= alpha;
        m_run = mnew;
      }
    }
    if (more) {   // QK(2*it+3) second half; write; prefetch K(2*it+4)
      s0 = mfma32(kc[4], qf[4], s0); s1 = mfma32(kc[5], qf[5], s1);
      s0 = mfma32(kc[6], qf[6], s0); s1 = mfma32(kc[7], qf[7], s1);
      WRS(s ^ 1, 1);
      int knB = (2 * it + 4 < 50) ? 2 * it + 4 : 0;
      LOADK(knB);
    }
#pragma unroll
    for (int r = 0; r < 16; ++r) p[r] = exp2v(p[r] - m_run);
    {
      float sSum = ((p[0] + p[1]) + (p[2] + p[3])) + ((p[4] + p[5]) + (p[6] + p[7])) +
                   (((p[8] + p[9]) + (p[10] + p[11])) + ((p[12] + p[13]) + (p[14] + p[15])));
      sSum += __shfl_xor(sSum, 32);
      l_run += sSum;
    }
    {
      unsigned x0 = cvtpk(p[0], p[1]), x1 = cvtpk(p[2], p[3]);
      unsigned y0 = cvtpk(p[4], p[5]), y1 = cvtpk(p[6], p[7]);
      PSWAP(x0, y0); PSWAP(x1, y1);
      uint4v u0 = {x0, x1, y0, y1};
      v8bf pf0 = __builtin_bit_cast(v8bf, u0);
      unsigned z0 = cvtpk(p[8], p[9]), z1 = cvtpk(p[10], p[11]);
      unsigned w0 = cvtpk(p[12], p[13]), w1 = cvtpk(p[14], p[15]);
      PSWAP(z0, w0); PSWAP(z1, w1);
      uint4v u1 = {z0, z1, w0, w1};
      v8bf pf1 = __builtin_bit_cast(v8bf, u1);
      // PV_B
      acc[0] = mfma32(vB0[0], pf0, acc[0]); acc[1] = mfma32(vB0[1], pf0, acc[1]);
      acc[2] = mfma32(vB0[2], pf0, acc[2]); acc[3] = mfma32(vB0[3], pf0, acc[3]);
      acc[0] = mfma32(vB1[0], pf1, acc[0]); acc[1] = mfma32(vB1[1], pf1, acc[1]);
      acc[2] = mfma32(vB1[2], pf1, acc[2]); acc[3] = mfma32(vB1[3], pf1, acc[3]);
    }
  }
#undef LOADK
#undef QKFULL
#undef WRS

  // epilogue: out = x + gamma * O / l   (own d-half; lanes = consecutive q)
  float inv = 1.f / l_run;
  float gm = gamma[0];
#pragma unroll
  for (int dd = 0; dd < 4; ++dd) {
#pragma unroll
    for (int r = 0; r < 16; ++r) {
      int d = (dto32 + dd) * 32 + (r & 3) + 8 * (r >> 2) + 4 * hi;
      size_t base = ((size_t)n * 256 + d) * HWP + q0 + l31;
      out[base] = x[base] + gm * acc[dd][r] * inv;
    }
  }
}

// ---------------- launcher ----------------
extern "C" void kernel_launch(void* const* d_in, const int* in_sizes, int n_in,
                              void* d_out, int out_size, void* d_ws, size_t ws_size,
                              hipStream_t stream) {
  const float* x     = (const float*)d_in[0];
  const float* ln_w  = (const float*)d_in[1];
  const float* ln_b  = (const float*)d_in[2];
  const float* qkv_w = (const float*)d_in[3];
  const float* qkv_b = (const float*)d_in[4];
  const float* gamma = (const float*)d_in[5];
  float* out = (float*)d_out;

  char* ws = (char*)d_ws;
  unsigned short* w_frag = (unsigned short*)ws;              //   393,216 B
  unsigned short* pe16   = (unsigned short*)(ws + 393216);   //   819,200 B (region 1.6 MB)
  unsigned short* q_arr  = (unsigned short*)(ws + 2031616);    // 13,107,200 B
  unsigned short* k_arr  = (unsigned short*)(ws + 15138816);   // 13,107,200 B
  unsigned short* v_arr  = (unsigned short*)(ws + 28246016);   // 13,107,200 B

  hipLaunchKernelGGL(prep_kernel, dim3(1024), dim3(256), 0, stream, qkv_w, pe16, w_frag);
  hipLaunchKernelGGL(ln_qkv_kernel, dim3(400), dim3(512), 0, stream,
                     x, ln_w, ln_b, w_frag, qkv_b, pe16, q_arr, k_arr, v_arr);
  hipLaunchKernelGGL(attn_kernel, dim3(800), dim3(128), 0, stream,
                     q_arr, k_arr, v_arr, x, gamma, out);
}

// Round 21
// 113.746 us; speedup vs baseline: 1.0285x; 1.0285x over previous
//
#include <hip/hip_runtime.h>
#include <hip/hip_bf16.h>

// ---------------- types ----------------
typedef float f32x4 __attribute__((ext_vector_type(4)));
typedef float f32x16 __attribute__((ext_vector_type(16)));
typedef __bf16 v8bf __attribute__((ext_vector_type(8)));
typedef unsigned short ushortx4 __attribute__((ext_vector_type(4)));
typedef unsigned short ushortx8 __attribute__((ext_vector_type(8)));
typedef unsigned int uint4v __attribute__((ext_vector_type(4)));

#define NIMG 16
#define CCH  256
#define HWP  1600

// q pre-scale: (1/sqrt(256)) * log2(e)  -> softmax runs in log2 domain (v_exp_f32 = 2^x)
#define QSCALE 0.09016844f
#define DEFER_THR 2.885390f   // 2.0 * log2(e)

__device__ __forceinline__ unsigned short f2bf(float f) {
  unsigned int u = __builtin_bit_cast(unsigned int, f);
  u = (u + 0x7FFFu + ((u >> 16) & 1u)) >> 16;
  return (unsigned short)u;
}
__device__ __forceinline__ float bf2f(unsigned short u) {
  return __builtin_bit_cast(float, (unsigned int)u << 16);
}

__device__ __forceinline__ f32x4 mfma16(v8bf a, v8bf b, f32x4 c) {
  return __builtin_amdgcn_mfma_f32_16x16x32_bf16(a, b, c, 0, 0, 0);
}
__device__ __forceinline__ f32x16 mfma32(v8bf a, v8bf b, f32x16 c) {
  return __builtin_amdgcn_mfma_f32_32x32x16_bf16(a, b, c, 0, 0, 0);
}

__device__ __forceinline__ unsigned cvtpk(float a, float b) {
  unsigned r;
  asm("v_cvt_pk_bf16_f32 %0, %1, %2" : "=v"(r) : "v"(a), "v"(b));
  return r;
}
__device__ __forceinline__ float exp2v(float x) {
  float r;
  asm("v_exp_f32 %0, %1" : "=v"(r) : "v"(x));
  return r;
}
__device__ __forceinline__ float sin2pi(float rev) {   // sin(2*pi*rev), rev >= 0
  float r;
  asm("v_fract_f32 %0, %1\n\tv_sin_f32 %0, %0" : "=v"(r) : "v"(rev));
  return r;
}
#define PSWAP(a, b) asm("v_permlane32_swap_b32 %0, %1" : "+v"(a), "+v"(b))

// ---------------- kernel A: weight->bf16 frag repack + PE table (bf16, native trig) --------
__global__ void prep_kernel(const float* __restrict__ qkv_w,
                            unsigned short* __restrict__ pe16,
                            unsigned short* __restrict__ w_frag) {
  int tid = blockIdx.x * blockDim.x + threadIdx.x;
  int nthr = gridDim.x * blockDim.x;
  for (int i = tid; i < 768 * 256; i += nthr) {
    int o = i >> 8, c = i & 255;
    int tile = o >> 4, lr = o & 15;
    int ks = c >> 5, lg = (c >> 3) & 3, e = c & 7;
    w_frag[(((size_t)tile * 8 + ks) * 64 + lg * 16 + lr) * 8 + e] = f2bf(qkv_w[i]);
  }
  const float oc = 0.20762051f;        // log2(10000)/64
  const float inv2pi = 0.15915494f;    // 1/(2*pi)
  for (int i = tid; i < HWP * 256; i += nthr) {
    int p = i >> 8, c = i & 255;
    int j = p % 40, ii = p / 40;             // x = j (col), y = ii (row)
    int tt = c & 63;
    float omega = exp2v(-(float)tt * oc) * inv2pi;
    float coord = (c < 128) ? (float)j : (float)ii;
    float rev = coord * omega;               // angle in revolutions
    if (c & 64) rev += 0.25f;                // cos(x) = sin(x + pi/2)
    pe16[i] = f2bf(sin2pi(rev));
  }
}

// ---------------- kernel B: LN + QKV GEMM + PE, direct frag-layout stores ----------------
// x read ONCE (kept in xv[32] registers across the LN stats phase; dead before GEMM).
// PE table is bf16 and loaded ONCE per (pix,c) -> shared by the q and k epilogues.
__global__ __launch_bounds__(512, 4) void ln_qkv_kernel(
    const float* __restrict__ x, const float* __restrict__ ln_w, const float* __restrict__ ln_b,
    const unsigned short* __restrict__ w_frag, const float* __restrict__ qkv_b,
    const unsigned short* __restrict__ pe16,
    unsigned short* __restrict__ q_arr, unsigned short* __restrict__ k_arr,
    unsigned short* __restrict__ v_arr) {
  __shared__ unsigned short bufraw[18432];     // 36,864 B
  __shared__ float red_s[8][64], red_q[8][64];
  __shared__ float mu_s[64], rs_s[64];

  int t = threadIdx.x;
  int n = blockIdx.x / 25, pt = blockIdx.x % 25;
  int pix0 = pt * 64;
  int p = t & 63, g = t >> 6;
  const float* xb = x + (size_t)n * CCH * HWP + pix0;

  // pass 1: LN stats; x kept in registers (single HBM read)
  float xv[32];
  {
    float sum = 0.f, sq = 0.f;
#pragma unroll
    for (int i = 0; i < 32; ++i) {
      float v = xb[(size_t)(g * 32 + i) * HWP + p];
      xv[i] = v; sum += v; sq += v * v;
    }
    red_s[g][p] = sum; red_q[g][p] = sq;
  }
  __syncthreads();
  if (t < 64) {
    float s = 0.f, q2 = 0.f;
#pragma unroll
    for (int gg = 0; gg < 8; ++gg) { s += red_s[gg][t]; q2 += red_q[gg][t]; }
    float mu = s * (1.f / 256.f);
    float var = q2 * (1.f / 256.f) - mu * mu;
    mu_s[t] = mu;
    rs_s[t] = rsqrtf(var + 1e-5f);
  }
  __syncthreads();
  {
    float mu = mu_s[p], rs = rs_s[p];
    int p7 = p & 7;
#pragma unroll
    for (int i4 = 0; i4 < 8; ++i4) {
      int c0 = g * 32 + i4 * 4;
      f32x4 lw = *(const f32x4*)&ln_w[c0];
      f32x4 lb = *(const f32x4*)&ln_b[c0];
      ushortx4 pk;
#pragma unroll
      for (int r = 0; r < 4; ++r)
        pk[r] = f2bf((xv[i4 * 4 + r] - mu) * rs * lw[r] + lb[r]);
      int unit = (c0 >> 3) ^ p7;             // swizzled 16B unit
      *(ushortx4*)&bufraw[p * 256 + unit * 8 + (i4 & 1) * 4] = pk;
    }
  }
  __syncthreads();

  // GEMM: A = weights (frag-arranged global), B = x-tile (LDS, swizzled reads)
  int w = t >> 6, l = t & 63, lr = l & 15, lg = l >> 4;
  int lr7 = lr & 7;
  f32x4 acc[6][4];
#pragma unroll
  for (int nf = 0; nf < 6; ++nf)
#pragma unroll
    for (int mi = 0; mi < 4; ++mi) acc[nf][mi] = (f32x4){0.f, 0.f, 0.f, 0.f};

#pragma unroll
  for (int ks = 0; ks < 8; ++ks) {
    v8bf bF[4];
#pragma unroll
    for (int mi = 0; mi < 4; ++mi)
      bF[mi] = *(const v8bf*)&bufraw[(mi * 16 + lr) * 256 + (((ks * 4 + lg) ^ lr7) * 8)];
#pragma unroll
    for (int nf = 0; nf < 6; ++nf) {
      int tile = w + nf * 8;
      v8bf wf = *(const v8bf*)&w_frag[(((size_t)tile * 8 + ks) * 64 + l) * 8];
#pragma unroll
      for (int mi = 0; mi < 4; ++mi) acc[nf][mi] = mfma16(wf, bF[mi], acc[nf][mi]);
    }
  }
  __syncthreads();   // A-tile dead chip-wide; bufraw reused as V stage

  // epilogue: acc[nf][mi][r] -> channel o = tile*16+lg*4+r, pixel pix0+mi*16+lr
  int lgh = lg >> 1, lgl = lg & 1;

  // ---- v (tiles 32..47): +bias -> wave-private LDS transpose stage ----
#pragma unroll
  for (int nf = 4; nf < 6; ++nf) {
    int tile = w + nf * 8;
    f32x4 bi = *(const f32x4*)&qkv_b[tile * 16 + lg * 4];
    int chb = (nf - 4) * 16 + lg * 4;
#pragma unroll
    for (int mi = 0; mi < 4; ++mi) {
      int pixl = mi * 16 + lr;
      f32x4 vv = acc[nf][mi] + bi;
#pragma unroll
      for (int r = 0; r < 4; ++r)
        bufraw[(w * 32 + chb + r) * 72 + pixl] = f2bf(vv[r]);
    }
  }

  // ---- q (tiles 0..15) + k (tiles 16..31): shared PE load (identical values) ----
#pragma unroll
  for (int nf = 0; nf < 2; ++nf) {
    int tile = w + nf * 8;          // q tile; k tile = tile+16, same pe slice
    int c4 = tile * 16 + lg * 4;
    f32x4 biq = *(const f32x4*)&qkv_b[c4];
    f32x4 bik = *(const f32x4*)&qkv_b[256 + c4];
#pragma unroll
    for (int mi = 0; mi < 4; ++mi) {
      int pix = pix0 + mi * 16 + lr;
      ushortx4 pu = *(const ushortx4*)&pe16[(size_t)pix * 256 + c4];
      f32x4 pev = {bf2f(pu[0]), bf2f(pu[1]), bf2f(pu[2]), bf2f(pu[3])};
      // q
      f32x4 vq = (acc[nf][mi] + biq + pev) * QSCALE;
      ushortx4 pkq = {f2bf(vq[0]), f2bf(vq[1]), f2bf(vq[2]), f2bf(vq[3])};
      int qt = pix >> 5, l31 = pix & 31;
      size_t adq = ((((size_t)n * 50 + qt) * 16 + tile) * 2 + lgh) * 256 + l31 * 8 + lgl * 4;
      *(ushortx4*)&q_arr[adq] = pkq;
      // k
      f32x4 vk = acc[nf + 2][mi] + bik + pev;
      ushortx4 pkk = {f2bf(vk[0]), f2bf(vk[1]), f2bf(vk[2]), f2bf(vk[3])};
      size_t adk = (((size_t)n * 16 + tile) * 1600 + pix) * 16 + lgh * 8 + lgl * 4;
      *(ushortx4*)&k_arr[adk] = pkk;
    }
  }

  // ---- v readback: 16B chunks from own wave's stage -> coalesced stores ----
#pragma unroll
  for (int c = 0; c < 4; ++c) {
    int ch = l & 31;                    // 0..31
    int pg = (l >> 5) + c * 2;          // 0..7
    ushortx8 vv = *(const ushortx8*)&bufraw[(w * 32 + ch) * 72 + pg * 8];
    int kvsl = pg >> 1, hi2 = pg & 1;
    int d = (ch & 15) + w * 16 + (ch >> 4) * 128;
    size_t di = (((size_t)n * 100 + pt * 4 + kvsl) * 2 + hi2) * 256 + d;
    *(ushortx8*)&v_arr[di * 8] = vv;
  }
}

// ---------------- kernel C: flash attention, 2 waves/block, D-split (r15 structure) --------
// KVBLK=64 per barrier: each iteration processes TWO 32-kv tiles (A,B) with ONE
// lgkmcnt-only barrier. S partials written to LDS and read back by BOTH waves
// (fixed-order add -> bit-identical softmax, no final merge). QK for the NEXT
// pair interleaved around the rescale branch; K single-buffered; V staggered.
__global__ __launch_bounds__(128, 2) void attn_kernel(
    const unsigned short* __restrict__ q_arr, const unsigned short* __restrict__ k_arr,
    const unsigned short* __restrict__ v_arr, const float* __restrict__ x,
    const float* __restrict__ gamma, float* __restrict__ out) {
  __shared__ float sx[2][2][2][4][64][4];   // [slot][tileAB][wave][r4][lane][4] = 32 KB

  int t = threadIdx.x;
  int wv = t >> 6, l = t & 63;
  int l31 = l & 31, hi = l >> 5;
  int dto = wv * 8;      // 16-wide d-tile offset for q/k frags
  int dto32 = wv * 4;    // 32-wide d-tile offset for v/acc
  int slot = blockIdx.x & 7, j = blockIdx.x >> 3;   // j in 0..99
  int n = slot + 8 * (j / 50);
  int qt = j % 50;
  int q0 = qt * 32;

  v8bf qf[8];
  {
    const unsigned short* qp = q_arr + (((size_t)n * 50 + qt) * 32 + hi) * 256 + l31 * 8;
#pragma unroll
    for (int i = 0; i < 8; ++i)
      qf[i] = *(const v8bf*)(qp + (dto + i) * 512);
  }

  f32x16 acc[4];
#pragma unroll
  for (int dd = 0; dd < 4; ++dd)
#pragma unroll
    for (int r = 0; r < 16; ++r) acc[dd][r] = 0.f;

  float m_run = -1e30f, l_run = 0.f;

  const unsigned short* kbase = k_arr + (size_t)n * (16 * 1600 * 16) +
                                (size_t)dto * 25600 + hi * 8;
  const unsigned short* vbase = v_arr + (size_t)n * (100 * 2 * 256 * 8) +
                                hi * 2048 + l31 * 8 + dto32 * 256;

  v8bf kc[8];
  f32x16 s0, s1;

#define LOADK(TT)                                                              \
  {                                                                            \
    _Pragma("unroll")                                                          \
    for (int i = 0; i < 8; ++i)                                                \
      kc[i] = *(const v8bf*)(kbase + (size_t)i * 25600 + ((TT) * 32 + l31) * 16); \
  }
#define QKFULL()                                                               \
  {                                                                            \
    _Pragma("unroll")                                                          \
    for (int r = 0; r < 16; ++r) { s0[r] = 0.f; s1[r] = 0.f; }                 \
    _Pragma("unroll")                                                          \
    for (int i = 0; i < 8; i += 2) {                                           \
      s0 = mfma32(kc[i], qf[i], s0);                                           \
      s1 = mfma32(kc[i + 1], qf[i + 1], s1);                                   \
    }                                                                          \
  }
#define WRS(SL, TI)                                                            \
  {                                                                            \
    _Pragma("unroll")                                                          \
    for (int r4 = 0; r4 < 4; ++r4) {                                           \
      f32x4 vv = {s0[r4 * 4 + 0] + s1[r4 * 4 + 0], s0[r4 * 4 + 1] + s1[r4 * 4 + 1], \
                  s0[r4 * 4 + 2] + s1[r4 * 4 + 2], s0[r4 * 4 + 3] + s1[r4 * 4 + 3]}; \
      *(f32x4*)&sx[SL][TI][wv][r4][l][0] = vv;                                 \
    }                                                                          \
  }

  // ---- prologue: QK(0), QK(1) -> slot 0; kc <- K(2); vA <- V(0) ----
  LOADK(0); QKFULL(); WRS(0, 0);
  LOADK(1); QKFULL(); WRS(0, 1);
  LOADK(2);
  v8bf vA0[4], vA1[4], vB0[4], vB1[4];
#pragma unroll
  for (int i = 0; i < 4; ++i) vA0[i] = *(const v8bf*)(vbase + i * 256);
#pragma unroll
  for (int i = 0; i < 4; ++i) vA1[i] = *(const v8bf*)(vbase + 4096 + i * 256);

  for (int it = 0; it < 25; ++it) {
    int s = it & 1;
    bool more = (it < 24);
    asm volatile("s_waitcnt lgkmcnt(0)" ::: "memory");
    __builtin_amdgcn_s_barrier();

    // ================= tile A = 2*it =================
    float p[16];
#pragma unroll
    for (int r4 = 0; r4 < 4; ++r4) {
      f32x4 a = *(const f32x4*)&sx[s][0][0][r4][l][0];
      f32x4 b = *(const f32x4*)&sx[s][0][1][r4][l][0];
#pragma unroll
      for (int rr = 0; rr < 4; ++rr) p[r4 * 4 + rr] = a[rr] + b[rr];
    }
    if (more) {   // QK(2*it+2) first half (MFMA pipe || VALU below)
#pragma unroll
      for (int r = 0; r < 16; ++r) { s0[r] = 0.f; s1[r] = 0.f; }
      s0 = mfma32(kc[0], qf[0], s0); s1 = mfma32(kc[1], qf[1], s1);
      s0 = mfma32(kc[2], qf[2], s0); s1 = mfma32(kc[3], qf[3], s1);
    }
    {
      float t0 = fmaxf(p[0], p[1]), t1 = fmaxf(p[2], p[3]);
      float t2 = fmaxf(p[4], p[5]), t3 = fmaxf(p[6], p[7]);
      float t4 = fmaxf(p[8], p[9]), t5 = fmaxf(p[10], p[11]);
      float t6 = fmaxf(p[12], p[13]), t7 = fmaxf(p[14], p[15]);
      float mx = fmaxf(fmaxf(fmaxf(t0, t1), fmaxf(t2, t3)),
                       fmaxf(fmaxf(t4, t5), fmaxf(t6, t7)));
      mx = fmaxf(mx, __shfl_xor(mx, 32));
      if (!__all(mx <= m_run + DEFER_THR)) {
        float mnew = fmaxf(m_run, mx);
        float alpha = exp2v(m_run - mnew);
        l_run *= alpha;
#pragma unroll
        for (int dd = 0; dd < 4; ++dd)
#pragma unroll
          for (int r = 0; r < 16; ++r) acc[dd][r] *= alpha;
        m_run = mnew;
      }
    }
    if (more) {   // QK(2*it+2) second half; write; prefetch K(2*it+3)
      s0 = mfma32(kc[4], qf[4], s0); s1 = mfma32(kc[5], qf[5], s1);
      s0 = mfma32(kc[6], qf[6], s0); s1 = mfma32(kc[7], qf[7], s1);
      WRS(s ^ 1, 0);
      LOADK(2 * it + 3);
    }
#pragma unroll
    for (int r = 0; r < 16; ++r) p[r] = exp2v(p[r] - m_run);
    {
      float sSum = ((p[0] + p[1]) + (p[2] + p[3])) + ((p[4] + p[5]) + (p[6] + p[7])) +
                   (((p[8] + p[9]) + (p[10] + p[11])) + ((p[12] + p[13]) + (p[14] + p[15])));
      sSum += __shfl_xor(sSum, 32);
      l_run += sSum;
    }
    {
      unsigned x0 = cvtpk(p[0], p[1]), x1 = cvtpk(p[2], p[3]);
      unsigned y0 = cvtpk(p[4], p[5]), y1 = cvtpk(p[6], p[7]);
      PSWAP(x0, y0); PSWAP(x1, y1);
      uint4v u0 = {x0, x1, y0, y1};
      v8bf pf0 = __builtin_bit_cast(v8bf, u0);
      unsigned z0 = cvtpk(p[8], p[9]), z1 = cvtpk(p[10], p[11]);
      unsigned w0 = cvtpk(p[12], p[13]), w1 = cvtpk(p[14], p[15]);
      PSWAP(z0, w0); PSWAP(z1, w1);
      uint4v u1 = {z0, z1, w0, w1};
      v8bf pf1 = __builtin_bit_cast(v8bf, u1);
      // PV_A
      acc[0] = mfma32(vA0[0], pf0, acc[0]); acc[1] = mfma32(vA0[1], pf0, acc[1]);
      acc[2] = mfma32(vA0[2], pf0, acc[2]); acc[3] = mfma32(vA0[3], pf0, acc[3]);
      acc[0] = mfma32(vA1[0], pf1, acc[0]); acc[1] = mfma32(vA1[1], pf1, acc[1]);
      acc[2] = mfma32(vA1[2], pf1, acc[2]); acc[3] = mfma32(vA1[3], pf1, acc[3]);
    }
    // V_B <- V(2*it+1): consumed after softmax_B (~350 cyc slack)
    {
      const unsigned short* vp = vbase + (size_t)(2 * it + 1) * 8192;
#pragma unroll
      for (int i = 0; i < 4; ++i) vB0[i] = *(const v8bf*)(vp + i * 256);
#pragma unroll
      for (int i = 0; i < 4; ++i) vB1[i] = *(const v8bf*)(vp + 4096 + i * 256);
    }

    // ================= tile B = 2*it+1 =================
#pragma unroll
    for (int r4 = 0; r4 < 4; ++r4) {
      f32x4 a = *(const f32x4*)&sx[s][1][0][r4][l][0];
      f32x4 b = *(const f32x4*)&sx[s][1][1][r4][l][0];
#pragma unroll
      for (int rr = 0; rr < 4; ++rr) p[r4 * 4 + rr] = a[rr] + b[rr];
    }
    if (more) {   // QK(2*it+3) first half
#pragma unroll
      for (int r = 0; r < 16; ++r) { s0[r] = 0.f; s1[r] = 0.f; }
      s0 = mfma32(kc[0], qf[0], s0); s1 = mfma32(kc[1], qf[1], s1);
      s0 = mfma32(kc[2], qf[2], s0); s1 = mfma32(kc[3], qf[3], s1);
    }
    {
      float t0 = fmaxf(p[0], p[1]), t1 = fmaxf(p[2], p[3]);
      float t2 = fmaxf(p[4], p[5]), t3 = fmaxf(p[6], p[7]);
      float t4 = fmaxf(p[8], p[9]), t5 = fmaxf(p[10], p[11]);
      float t6 = fmaxf(p[12], p[13]), t7 = fmaxf(p[14], p[15]);
      float mx = fmaxf(fmaxf(fmaxf(t0, t1), fmaxf(t2, t3)),
                       fmaxf(fmaxf(t4, t5), fmaxf(t6, t7)));
      mx = fmaxf(mx, __shfl_xor(mx, 32));
      if (!__all(mx <= m_run + DEFER_THR)) {
        float mnew = fmaxf(m_run, mx);
        float alpha = exp2v(m_run - mnew);
        l_run *= alpha;
#pragma unroll
        for (int dd = 0; dd < 4; ++dd)
#pragma unroll
          for (int r = 0; r < 16; ++r) acc[dd][r] *= alpha;
        m_run = mnew;
      }
    }
    if (more) {   // QK(2*it+3) second half; write; prefetch K(2*it+4)
      s0 = mfma32(kc[4], qf[4], s0); s1 = mfma32(kc[5], qf[5], s1);
      s0 = mfma32(kc[6], qf[6], s0); s1 = mfma32(kc[7], qf[7], s1);
      WRS(s ^ 1, 1);
      int knB = (2 * it + 4 < 50) ? 2 * it + 4 : 0;
      LOADK(knB);
    }
#pragma unroll
    for (int r = 0; r < 16; ++r) p[r] = exp2v(p[r] - m_run);
    {
      float sSum = ((p[0] + p[1]) + (p[2] + p[3])) + ((p[4] + p[5]) + (p[6] + p[7])) +
                   (((p[8] + p[9]) + (p[10] + p[11])) + ((p[12] + p[13]) + (p[14] + p[15])));
      sSum += __shfl_xor(sSum, 32);
      l_run += sSum;
    }
    {
      unsigned x0 = cvtpk(p[0], p[1]), x1 = cvtpk(p[2], p[3]);
      unsigned y0 = cvtpk(p[4], p[5]), y1 = cvtpk(p[6], p[7]);
      PSWAP(x0, y0); PSWAP(x1, y1);
      uint4v u0 = {x0, x1, y0, y1};
      v8bf pf0 = __builtin_bit_cast(v8bf, u0);
      unsigned z0 = cvtpk(p[8], p[9]), z1 = cvtpk(p[10], p[11]);
      unsigned w0 = cvtpk(p[12], p[13]), w1 = cvtpk(p[14], p[15]);
      PSWAP(z0, w0); PSWAP(z1, w1);
      uint4v u1 = {z0, z1, w0, w1};
      v8bf pf1 = __builtin_bit_cast(v8bf, u1);
      // PV_B
      acc[0] = mfma32(vB0[0], pf0, acc[0]); acc[1] = mfma32(vB0[1], pf0, acc[1]);
      acc[2] = mfma32(vB0[2], pf0, acc[2]); acc[3] = mfma32(vB0[3], pf0, acc[3]);
      acc[0] = mfma32(vB1[0], pf1, acc[0]); acc[1] = mfma32(vB1[1], pf1, acc[1]);
      acc[2] = mfma32(vB1[2], pf1, acc[2]); acc[3] = mfma32(vB1[3], pf1, acc[3]);
    }
    if (more) {
      // V_A <- V(2*it+2): consumed next iter after softmax_A (~full-iter slack)
      const unsigned short* vp = vbase + (size_t)(2 * it + 2) * 8192;
#pragma unroll
      for (int i = 0; i < 4; ++i) vA0[i] = *(const v8bf*)(vp + i * 256);
#pragma unroll
      for (int i = 0; i < 4; ++i) vA1[i] = *(const v8bf*)(vp + 4096 + i * 256);
    }
  }
#undef LOADK
#undef QKFULL
#undef WRS

  // epilogue: out = x + gamma * O / l   (own d-half; lanes = consecutive q)
  float inv = 1.f / l_run;
  float gm = gamma[0];
#pragma unroll
  for (int dd = 0; dd < 4; ++dd) {
#pragma unroll
    for (int r = 0; r < 16; ++r) {
      int d = (dto32 + dd) * 32 + (r & 3) + 8 * (r >> 2) + 4 * hi;
      size_t base = ((size_t)n * 256 + d) * HWP + q0 + l31;
      out[base] = x[base] + gm * acc[dd][r] * inv;
    }
  }
}

// ---------------- launcher ----------------
extern "C" void kernel_launch(void* const* d_in, const int* in_sizes, int n_in,
                              void* d_out, int out_size, void* d_ws, size_t ws_size,
                              hipStream_t stream) {
  const float* x     = (const float*)d_in[0];
  const float* ln_w  = (const float*)d_in[1];
  const float* ln_b  = (const float*)d_in[2];
  const float* qkv_w = (const float*)d_in[3];
  const float* qkv_b = (const float*)d_in[4];
  const float* gamma = (const float*)d_in[5];
  float* out = (float*)d_out;

  char* ws = (char*)d_ws;
  unsigned short* w_frag = (unsigned short*)ws;              //   393,216 B
  unsigned short* pe16   = (unsigned short*)(ws + 393216);   //   819,200 B (region 1.6 MB)
  unsigned short* q_arr  = (unsigned short*)(ws + 2031616);    // 13,107,200 B
  unsigned short* k_arr  = (unsigned short*)(ws + 15138816);   // 13,107,200 B
  unsigned short* v_arr  = (unsigned short*)(ws + 28246016);   // 13,107,200 B

  hipLaunchKernelGGL(prep_kernel, dim3(1024), dim3(256), 0, stream, qkv_w, pe16, w_frag);
  hipLaunchKernelGGL(ln_qkv_kernel, dim3(400), dim3(512), 0, stream,
                     x, ln_w, ln_b, w_frag, qkv_b, pe16, q_arr, k_arr, v_arr);
  hipLaunchKernelGGL(attn_kernel, dim3(800), dim3(128), 0, stream,
                     q_arr, k_arr, v_arr, x, gamma, out);
}